// Round 8
// baseline (294.052 us; speedup 1.0000x reference)
//
#include <hip/hip_runtime.h>
#include <hip/hip_bf16.h>

// Problem dims (fixed by reference)
#define BATCH 128
#define PIX   196
#define EDIM  2048
#define DDIM  512
#define ADIM  512
#define MTOT  (BATCH*PIX)   // 25088
#define BK    32
#define NK    (EDIM/BK)     // 64
#define BM    64            // rows per block
#define NSLC  2             // N split: 2 slices of 256

typedef __attribute__((ext_vector_type(8))) short short8;
typedef __attribute__((ext_vector_type(4))) float f32x4;

__device__ __forceinline__ unsigned short f2bf(float f) {
    union { float f; unsigned int u; } c; c.f = f;
    unsigned int u = c.u;
    u += 0x7fffu + ((u >> 16) & 1u);   // round-to-nearest-even
    return (unsigned short)(u >> 16);
}

// Hardware cvt (v_cvt_pk_bf16_f32; RNE, matches f2bf)
__device__ __forceinline__ short8 cvt8(float4 a, float4 b) {
    short8 v;
    v[0] = (short)__bfloat16_as_ushort(__float2bfloat16(a.x));
    v[1] = (short)__bfloat16_as_ushort(__float2bfloat16(a.y));
    v[2] = (short)__bfloat16_as_ushort(__float2bfloat16(a.z));
    v[3] = (short)__bfloat16_as_ushort(__float2bfloat16(a.w));
    v[4] = (short)__bfloat16_as_ushort(__float2bfloat16(b.x));
    v[5] = (short)__bfloat16_as_ushort(__float2bfloat16(b.y));
    v[6] = (short)__bfloat16_as_ushort(__float2bfloat16(b.z));
    v[7] = (short)__bfloat16_as_ushort(__float2bfloat16(b.w));
    return v;
}

#define GLOAD16(gp, lp) __builtin_amdgcn_global_load_lds( \
    (const __attribute__((address_space(1))) void*)(gp),  \
    (__attribute__((address_space(3))) void*)(lp), 16, 0, 0)

#define MFMA16(a, b, c) __builtin_amdgcn_mfma_f32_16x16x32_bf16(a, b, c, 0, 0, 0)

// ---------------------------------------------------------------------------
// Kernel 0: pack W_enc [K=2048][A=512] fp32 into per-(kt,ns) 16KB images, bf16.
// Image (kt,ns): byte c*16 (c=0..1023): jj=c>>6, l=c&63; holds bf16 of
// W_enc[kt*32 + (l>>4)*8 + d][ns*256 + jj*16 + (l&15)], d=0..7.
// gemm frag read = jj*1024 + lane*16  (lane-linear: conflict-free).
// ---------------------------------------------------------------------------
__global__ __launch_bounds__(256) void pack_wenc(const float* __restrict__ Wenc,
                                                 unsigned short* __restrict__ WTp) {
    __shared__ float f[32 * ADIM];   // 64 KB: rows k=kt*32..+31
    const int kt = blockIdx.x;
    const int tid = threadIdx.x;
    const float4* src = (const float4*)(Wenc + (size_t)kt * 32 * ADIM);
    float4* dst = (float4*)f;
    #pragma unroll
    for (int i = 0; i < 16; ++i)
        dst[tid + i * 256] = src[tid + i * 256];
    __syncthreads();
    for (int c2 = tid; c2 < 2048; c2 += 256) {
        int ns = c2 >> 10;
        int c  = c2 & 1023;
        int jj = c >> 6;
        int l  = c & 63;
        int n  = ns * 256 + jj * 16 + (l & 15);
        int k0 = (l >> 4) * 8;
        short8 v;
        #pragma unroll
        for (int d = 0; d < 8; ++d)
            v[d] = (short)f2bf(f[(k0 + d) * ADIM + n]);
        *(short8*)(WTp + (size_t)kt * 16384 + (size_t)c2 * 8) = v;
    }
}

// ---------------------------------------------------------------------------
// Kernel 1: bias[b][a] = sum_d dec[b][d]*Wdec[d][a] + b_dec[a] + b_enc[a]
// ---------------------------------------------------------------------------
__global__ __launch_bounds__(256) void bias_kernel(const float* __restrict__ dec,
                                                   const float* __restrict__ Wdec,
                                                   const float* __restrict__ b_enc,
                                                   const float* __restrict__ b_dec,
                                                   float* __restrict__ bias) {
    __shared__ float ds[4 * DDIM];
    const int b0 = blockIdx.x * 4;
    for (int i = threadIdx.x; i < 4 * DDIM; i += 256)
        ds[i] = dec[(size_t)b0 * DDIM + i];
    __syncthreads();
    const int a0 = threadIdx.x * 2;
    float acc0[4] = {0.f, 0.f, 0.f, 0.f};
    float acc1[4] = {0.f, 0.f, 0.f, 0.f};
    for (int d = 0; d < DDIM; d++) {
        float2 w = *(const float2*)&Wdec[(size_t)d * ADIM + a0];
        #pragma unroll
        for (int bi = 0; bi < 4; bi++) {
            float dv = ds[bi * DDIM + d];
            acc0[bi] += dv * w.x;
            acc1[bi] += dv * w.y;
        }
    }
    float be0 = b_enc[a0] + b_dec[a0];
    float be1 = b_enc[a0 + 1] + b_dec[a0 + 1];
    #pragma unroll
    for (int bi = 0; bi < 4; bi++) {
        bias[(size_t)(b0 + bi) * ADIM + a0]     = acc0[bi] + be0;
        bias[(size_t)(b0 + bi) * ADIM + a0 + 1] = acc1[bi] + be1;
    }
}

// ---------------------------------------------------------------------------
// Kernel 2: fused att1 GEMM + relu + dot(W_full) -> att_part[ns][m]
// Block = 64M x 256N x fullK, 4 waves (2M x 2N), wave tile 32x128.
// Grid 784 = 392 m-groups x 2 slices; XCD-swizzled so the 2 twins share an
// XCD (A-panel re-read hits that XCD's L2). 3 blocks/CU resident.
// B: packed images via global_load_lds, ring-3 (48KB). A: global->reg,
// 2-deep even/odd buffers. Steady state waits only on loads issued a full
// iter earlier: vmcnt(12)/vmcnt(12). Never drains in-loop.
// ---------------------------------------------------------------------------
__global__ __launch_bounds__(256, 3) void gemm_att(const float* __restrict__ enc,
                                                   const unsigned short* __restrict__ WTp,
                                                   const float* __restrict__ bias,
                                                   const float* __restrict__ Wfull,
                                                   float* __restrict__ att_part) {
    __shared__ __align__(16) char ldsB[3][16384];
    __shared__ float red[2][BM];

    const int tid  = threadIdx.x;
    const int lane = tid & 63;
    const int wid  = tid >> 6;          // 0..3
    const int wm   = wid >> 1;          // 0..1 (M half)
    const int wn   = wid & 1;           // 0..1 (N half)
    const int cif  = lane & 15;
    const int rgrp = lane >> 4;

    // XCD swizzle: raw = q*16 + ns*8 + xcd ; g = q*8 + xcd. Twins are 8
    // dispatch slots apart -> same XCD (round-robin), adjacent in its queue.
    const int raw = blockIdx.x;
    const int g   = (raw >> 4) * 8 + (raw & 7);
    const int ns  = (raw >> 3) & 1;
    const int m0  = g * BM;

    // B staging: wave wid copies bytes [wid*4096, +4096) of each 16KB image
    const char* pB = (const char*)WTp + (size_t)ns * 16384 + (size_t)wid * 4096
                   + (size_t)lane * 16;
    const unsigned bOff = (unsigned)(wid * 4096 + lane * 16);

    // A: lane covers rows m0 + wm*32 + i*16 + cif (i=0,1), k-chunk rgrp*8
    const float* pA0 = enc + (size_t)(m0 + wm * 32 + cif) * EDIM + rgrp * 8;
    const float* pA1 = pA0 + (size_t)16 * EDIM;

    char* bR  = ldsB[0];
    char* bN1 = ldsB[1];
    char* bN2 = ldsB[2];

    f32x4 acc[2][8] = {};
    float4 aA[4], aB[4];   // even / odd A reg buffers (A(kt), A(kt+1))

    // ---- prologue: B(0),A(0),B(1),A(1) issued; wait B(0) only ----
    #pragma unroll
    for (int c = 0; c < 4; ++c)
        GLOAD16(pB + c * 1024, bR + bOff + c * 1024);
    aA[0] = *(const float4*)pA0; aA[1] = *(const float4*)(pA0 + 4);
    aA[2] = *(const float4*)pA1; aA[3] = *(const float4*)(pA1 + 4);
    #pragma unroll
    for (int c = 0; c < 4; ++c)
        GLOAD16(pB + 32768 + c * 1024, bN1 + bOff + c * 1024);
    {
        const float* q0 = pA0 + BK; const float* q1 = pA1 + BK;
        aB[0] = *(const float4*)q0; aB[1] = *(const float4*)(q0 + 4);
        aB[2] = *(const float4*)q1; aB[3] = *(const float4*)(q1 + 4);
    }
    asm volatile("s_waitcnt vmcnt(12)" ::: "memory");   // B(0) done
    __builtin_amdgcn_s_barrier();
    __builtin_amdgcn_sched_barrier(0);

    // One pipeline iteration. AR = buffer holding A(kt); refilled with A(kt+2).
#define GITER(KT, AR)                                                          \
    do {                                                                       \
        const char* ps_ = pB + (size_t)(KT + 2) * 32768;                       \
        GLOAD16(ps_,        bN2 + bOff);                                       \
        GLOAD16(ps_ + 1024, bN2 + bOff + 1024);                                \
        GLOAD16(ps_ + 2048, bN2 + bOff + 2048);                                \
        GLOAD16(ps_ + 3072, bN2 + bOff + 3072);                                \
        asm volatile("s_waitcnt vmcnt(12)" ::: "memory"); /* A(KT) landed */   \
        short8 ac0_ = cvt8(AR[0], AR[1]);                                      \
        short8 ac1_ = cvt8(AR[2], AR[3]);                                      \
        {                                                                      \
            const float* q0_ = pA0 + (KT + 2) * BK;                            \
            const float* q1_ = pA1 + (KT + 2) * BK;                            \
            AR[0] = *(const float4*)q0_; AR[1] = *(const float4*)(q0_ + 4);    \
            AR[2] = *(const float4*)q1_; AR[3] = *(const float4*)(q1_ + 4);    \
        }                                                                      \
        short8 b_[8];                                                          \
        _Pragma("unroll")                                                      \
        for (int j = 0; j < 8; ++j)                                            \
            b_[j] = *(const short8*)(bR + (wn * 8 + j) * 1024 + lane * 16);    \
        __builtin_amdgcn_s_setprio(1);                                         \
        _Pragma("unroll")                                                      \
        for (int j = 0; j < 8; ++j) {                                          \
            acc[0][j] = MFMA16(ac0_, b_[j], acc[0][j]);                        \
            acc[1][j] = MFMA16(ac1_, b_[j], acc[1][j]);                        \
        }                                                                      \
        __builtin_amdgcn_s_setprio(0);                                         \
        asm volatile("s_waitcnt vmcnt(12)" ::: "memory"); /* B(KT+1) done */   \
        __builtin_amdgcn_s_barrier();                                          \
        __builtin_amdgcn_sched_barrier(0);                                     \
        { char* t_ = bR; bR = bN1; bN1 = bN2; bN2 = t_; }                      \
    } while (0)

    // ---- main loop: kt = 0 .. NK-3 (62 iters, explicit even/odd) ----
    for (int kt = 0; kt < NK - 2; kt += 2) {
        GITER(kt, aA);
        GITER(kt + 1, aB);
    }
#undef GITER

    // ---- peeled kt = NK-2 ----
    {
        asm volatile("s_waitcnt vmcnt(8)" ::: "memory");    // A(NK-2) done
        short8 ac0 = cvt8(aA[0], aA[1]);
        short8 ac1 = cvt8(aA[2], aA[3]);
        short8 b[8];
        #pragma unroll
        for (int j = 0; j < 8; ++j)
            b[j] = *(const short8*)(bR + (wn * 8 + j) * 1024 + lane * 16);
        __builtin_amdgcn_s_setprio(1);
        #pragma unroll
        for (int j = 0; j < 8; ++j) {
            acc[0][j] = MFMA16(ac0, b[j], acc[0][j]);
            acc[1][j] = MFMA16(ac1, b[j], acc[1][j]);
        }
        __builtin_amdgcn_s_setprio(0);
        asm volatile("s_waitcnt vmcnt(4)" ::: "memory");    // B(NK-1) done
        __builtin_amdgcn_s_barrier();
        __builtin_amdgcn_sched_barrier(0);
        { char* t = bR; bR = bN1; bN1 = bN2; bN2 = t; }
    }
    // ---- peeled kt = NK-1 ----
    {
        asm volatile("s_waitcnt vmcnt(0)" ::: "memory");
        short8 ac0 = cvt8(aB[0], aB[1]);
        short8 ac1 = cvt8(aB[2], aB[3]);
        short8 b[8];
        #pragma unroll
        for (int j = 0; j < 8; ++j)
            b[j] = *(const short8*)(bR + (wn * 8 + j) * 1024 + lane * 16);
        #pragma unroll
        for (int j = 0; j < 8; ++j) {
            acc[0][j] = MFMA16(ac0, b[j], acc[0][j]);
            acc[1][j] = MFMA16(ac1, b[j], acc[1][j]);
        }
    }

    // ---- epilogue: relu(acc + bias) . Wfull over this slice's 256 cols ----
    const int bf  = m0 / PIX;
    const int thr = (bf + 1) * PIX;
    const int bfc = (bf + 1 < BATCH) ? bf + 1 : BATCH - 1;
    float wf[8], bs0[8], bs1[8];
    #pragma unroll
    for (int j = 0; j < 8; ++j) {
        int aj = ns * 256 + wn * 128 + j * 16 + cif;
        wf[j]  = Wfull[aj];
        bs0[j] = bias[(size_t)bf  * ADIM + aj];
        bs1[j] = bias[(size_t)bfc * ADIM + aj];
    }
    #pragma unroll
    for (int i = 0; i < 2; ++i) {
        #pragma unroll
        for (int r = 0; r < 4; ++r) {
            int ml = wm * 32 + i * 16 + rgrp * 4 + r;
            int m  = m0 + ml;
            bool sec = (m >= thr);
            float s = 0.f;
            #pragma unroll
            for (int j = 0; j < 8; ++j) {
                float v = acc[i][j][r] + (sec ? bs1[j] : bs0[j]);
                s += fmaxf(v, 0.f) * wf[j];
            }
            s += __shfl_xor(s, 1);
            s += __shfl_xor(s, 2);
            s += __shfl_xor(s, 4);
            s += __shfl_xor(s, 8);
            if (cif == 0) red[wn][ml] = s;
        }
    }
    __syncthreads();
    if (tid < BM)
        att_part[(size_t)ns * MTOT + m0 + tid] = red[0][tid] + red[1][tid];
}

// ---------------------------------------------------------------------------
// Kernel 3: softmax over p; att = sum of 2 N-slice partials (b_full cancels)
// ---------------------------------------------------------------------------
__global__ __launch_bounds__(256) void softmax_kernel(const float* __restrict__ att_part,
                                                      float* __restrict__ alpha) {
    const int b = blockIdx.x;
    const int tid = threadIdx.x;
    const int lane = tid & 63, wid = tid >> 6;
    __shared__ float wred[4];

    float x = -1e30f;
    if (tid < PIX) {
        size_t m = (size_t)b * PIX + tid;
        x = att_part[m] + att_part[MTOT + m];
    }
    float mx = x;
    #pragma unroll
    for (int off = 32; off >= 1; off >>= 1) mx = fmaxf(mx, __shfl_xor(mx, off));
    if (lane == 0) wred[wid] = mx;
    __syncthreads();
    float gm = fmaxf(fmaxf(wred[0], wred[1]), fmaxf(wred[2], wred[3]));
    __syncthreads();

    float e = (tid < PIX) ? __expf(x - gm) : 0.f;
    float s = e;
    #pragma unroll
    for (int off = 32; off >= 1; off >>= 1) s += __shfl_xor(s, off);
    if (lane == 0) wred[wid] = s;
    __syncthreads();
    float gs = wred[0] + wred[1] + wred[2] + wred[3];

    if (tid < PIX) alpha[(size_t)b * PIX + tid] = e / gs;
}

// ---------------------------------------------------------------------------
// Kernel 4: out[b][e] = sum_p enc[b][p][e] * alpha[b][p]
// ---------------------------------------------------------------------------
__global__ __launch_bounds__(128) void weighted_kernel(const float* __restrict__ enc,
                                                       const float* __restrict__ alpha,
                                                       float* __restrict__ out) {
    const int b = blockIdx.x >> 2;
    const int q = blockIdx.x & 3;
    const int tid = threadIdx.x;
    __shared__ float al[PIX];
    for (int i = tid; i < PIX; i += 128) al[i] = alpha[(size_t)b * PIX + i];
    __syncthreads();

    const int e = q * 512 + tid * 4;
    const float4* src = (const float4*)(enc + (size_t)b * PIX * EDIM + e);
    float ax = 0.f, ay = 0.f, az = 0.f, aw = 0.f;
    #pragma unroll 4
    for (int p = 0; p < PIX; p++) {
        float av = al[p];
        float4 v = src[(size_t)p * (EDIM / 4)];
        ax += av * v.x; ay += av * v.y; az += av * v.z; aw += av * v.w;
    }
    float4 o; o.x = ax; o.y = ay; o.z = az; o.w = aw;
    *(float4*)&out[(size_t)b * EDIM + e] = o;
}

// ---------------------------------------------------------------------------
extern "C" void kernel_launch(void* const* d_in, const int* in_sizes, int n_in,
                              void* d_out, int out_size, void* d_ws, size_t ws_size,
                              hipStream_t stream) {
    const float* enc   = (const float*)d_in[0];   // [128,196,2048]
    const float* dec   = (const float*)d_in[1];   // [128,512]
    const float* Wenc  = (const float*)d_in[2];   // [2048,512]
    const float* benc  = (const float*)d_in[3];   // [512]
    const float* Wdec  = (const float*)d_in[4];   // [512,512]
    const float* bdec  = (const float*)d_in[5];   // [512]
    const float* Wfull = (const float*)d_in[6];   // [512]
    // d_in[7] = b_full: constant shift, cancels in softmax

    float* out_awe   = (float*)d_out;                       // [128,2048]
    float* out_alpha = (float*)d_out + BATCH * EDIM;        // [128,196]

    char* ws = (char*)d_ws;
    unsigned short* WTp = (unsigned short*)ws;                      // 2 MB packed images
    float* bias = (float*)(ws + (size_t)ADIM * EDIM * 2);           // 256 KB [128][512]
    float* att_part = (float*)(ws + (size_t)ADIM * EDIM * 2
                             + (size_t)BATCH * ADIM * 4);           // 2 x 100 KB

    pack_wenc<<<NK, 256, 0, stream>>>(Wenc, WTp);
    bias_kernel<<<BATCH / 4, 256, 0, stream>>>(dec, Wdec, benc, bdec, bias);
    gemm_att<<<(MTOT / BM) * NSLC, 256, 0, stream>>>(enc, WTp, bias, Wfull, att_part);
    softmax_kernel<<<BATCH, 256, 0, stream>>>(att_part, out_alpha);
    weighted_kernel<<<BATCH * 4, 128, 0, stream>>>(enc, out_alpha, out_awe);
}

// Round 9
// 132.725 us; speedup vs baseline: 2.2155x; 2.2155x over previous
//
#include <hip/hip_runtime.h>
#include <hip/hip_bf16.h>

// Problem dims (fixed by reference)
#define BATCH 128
#define PIX   196
#define EDIM  2048
#define DDIM  512
#define ADIM  512
#define MTOT  (BATCH*PIX)   // 25088
#define BK    32
#define NK    (EDIM/BK)     // 64

typedef __attribute__((ext_vector_type(8))) short short8;
typedef __attribute__((ext_vector_type(4))) float f32x4;

__device__ __forceinline__ unsigned short f2bf(float f) {
    union { float f; unsigned int u; } c; c.f = f;
    unsigned int u = c.u;
    u += 0x7fffu + ((u >> 16) & 1u);   // round-to-nearest-even
    return (unsigned short)(u >> 16);
}

__device__ __forceinline__ short8 cvt8(float4 a, float4 b) {
    short8 v;
    v[0] = (short)f2bf(a.x); v[1] = (short)f2bf(a.y);
    v[2] = (short)f2bf(a.z); v[3] = (short)f2bf(a.w);
    v[4] = (short)f2bf(b.x); v[5] = (short)f2bf(b.y);
    v[6] = (short)f2bf(b.z); v[7] = (short)f2bf(b.w);
    return v;
}

#define GLOAD16(gp, lp) __builtin_amdgcn_global_load_lds( \
    (const __attribute__((address_space(1))) void*)(gp),  \
    (__attribute__((address_space(3))) void*)(lp), 16, 0, 0)

#define MFMA16(a, b, c) __builtin_amdgcn_mfma_f32_16x16x32_bf16(a, b, c, 0, 0, 0)

// ---------------------------------------------------------------------------
// Kernel 0: pack W_enc [K=2048][A=512] fp32 -> per-kt 32KB images, bf16.
// Image kt, 16B slot c (c=0..2047): jj=c>>6 (0..31), l=c&63; holds bf16 of
// W_enc[kt*32 + (l>>4)*8 + d][jj*16 + (l&15)], d=0..7.
// gemm slurps linearly (wave-uniform LDS dest, HW adds lane*16);
// frag j read = jj*1024 + lane*16 -> ZERO bank conflicts (proven r8).
// ---------------------------------------------------------------------------
__global__ __launch_bounds__(256) void pack_wenc(const float* __restrict__ Wenc,
                                                 unsigned short* __restrict__ WTp) {
    __shared__ float f[32 * ADIM];   // 64 KB: rows k=kt*32..+31
    const int kt = blockIdx.x;
    const int tid = threadIdx.x;
    const float4* src = (const float4*)(Wenc + (size_t)kt * 32 * ADIM);
    float4* dst = (float4*)f;
    #pragma unroll
    for (int i = 0; i < 16; ++i)
        dst[tid + i * 256] = src[tid + i * 256];
    __syncthreads();
    for (int c = tid; c < 2048; c += 256) {
        int jj = c >> 6;
        int l  = c & 63;
        int n  = jj * 16 + (l & 15);
        int k0 = (l >> 4) * 8;
        short8 v;
        #pragma unroll
        for (int d = 0; d < 8; ++d)
            v[d] = (short)f2bf(f[(k0 + d) * ADIM + n]);
        *(short8*)(WTp + (size_t)kt * 16384 + (size_t)c * 8) = v;
    }
}

// ---------------------------------------------------------------------------
// Kernel 1: bias[b][a] = sum_d dec[b][d]*Wdec[d][a] + b_dec[a] + b_enc[a]
// ---------------------------------------------------------------------------
__global__ __launch_bounds__(256) void bias_kernel(const float* __restrict__ dec,
                                                   const float* __restrict__ Wdec,
                                                   const float* __restrict__ b_enc,
                                                   const float* __restrict__ b_dec,
                                                   float* __restrict__ bias) {
    __shared__ float ds[4 * DDIM];
    const int b0 = blockIdx.x * 4;
    for (int i = threadIdx.x; i < 4 * DDIM; i += 256)
        ds[i] = dec[(size_t)b0 * DDIM + i];
    __syncthreads();
    const int a0 = threadIdx.x * 2;
    float acc0[4] = {0.f, 0.f, 0.f, 0.f};
    float acc1[4] = {0.f, 0.f, 0.f, 0.f};
    for (int d = 0; d < DDIM; d++) {
        float2 w = *(const float2*)&Wdec[(size_t)d * ADIM + a0];
        #pragma unroll
        for (int bi = 0; bi < 4; bi++) {
            float dv = ds[bi * DDIM + d];
            acc0[bi] += dv * w.x;
            acc1[bi] += dv * w.y;
        }
    }
    float be0 = b_enc[a0] + b_dec[a0];
    float be1 = b_enc[a0 + 1] + b_dec[a0 + 1];
    #pragma unroll
    for (int bi = 0; bi < 4; bi++) {
        bias[(size_t)(b0 + bi) * ADIM + a0]     = acc0[bi] + be0;
        bias[(size_t)(b0 + bi) * ADIM + a0 + 1] = acc1[bi] + be1;
    }
}

// ---------------------------------------------------------------------------
// Kernel 2: fused att1 GEMM + relu + dot(W_full) -> att[m]
// Round-3 structure (proven best): 512 thr, 8 waves (2M x 4N), tile
// 128M x 512N x 32K, wave tile 64x128. B: packed images via global_load_lds
// (WAVE-UNIFORM LDS dest), ring-3. A: global->reg->cvt->ds_write, dbuf-2.
// Counted vmcnt(6) before each barrier; drains only in the 2 peeled iters.
// NEW vs round 3: lane*16-linear frag reads (0 bank conflicts).
// ---------------------------------------------------------------------------
__global__ __launch_bounds__(512, 2) void gemm_att(const float* __restrict__ enc,
                                                   const unsigned short* __restrict__ WTp,
                                                   const float* __restrict__ bias,
                                                   const float* __restrict__ Wfull,
                                                   float* __restrict__ att) {
    __shared__ __align__(16) char ldsA[2][8192];
    __shared__ __align__(16) char ldsB[3][32768];
    __shared__ float red[4][128];

    const int tid  = threadIdx.x;
    const int lane = tid & 63;
    const int wid  = tid >> 6;          // 0..7
    const int wm   = wid >> 2;          // 0..1
    const int wn   = wid & 3;           // 0..3
    const int cif  = lane & 15;
    const int rgrp = lane >> 4;
    const int m0   = blockIdx.x * 128;

    // A: thread t holds row r=t>>2 (global m0+r), k-chunk kc=t&3 (8 floats).
    // ds_write addr = (r>>4)*1024 + (kc*16 + (r&15))*16  (per-wave bijection
    // onto contiguous 1KB). Frag read i: (wm*4+i)*1024 + lane*16 (linear).
    const float* pA = enc + (size_t)(m0 + (tid >> 2)) * EDIM + (tid & 3) * 8;
    const unsigned aWoff = (unsigned)((tid >> 6) * 1024
                         + ((tid & 3) * 16 + ((tid >> 2) & 15)) * 16);
    // B: linear image copy; wave wid owns bytes [wid*4096, +4096) of each
    // 32KB image. LDS dest is WAVE-UNIFORM; HW adds lane*16.
    const char* pB = (const char*)WTp + (size_t)wid * 4096 + (size_t)lane * 16;
    const unsigned bgOff = (unsigned)(wid * 4096);

    char* aR = ldsA[0]; char* aW = ldsA[1];
    char* bR = ldsB[0]; char* bN1 = ldsB[1]; char* bN2 = ldsB[2];

    f32x4 acc[4][8] = {};
    float4 rg[2][2];

    // ---- prologue: A0,A1 reg-loaded; B0,B1 in flight; A0 staged ----
    float4 t0 = *(const float4*)pA;
    float4 t1 = *(const float4*)(pA + 4);
    rg[1][0] = *(const float4*)(pA + BK);
    rg[1][1] = *(const float4*)(pA + BK + 4);
    #pragma unroll
    for (int c = 0; c < 4; ++c)
        GLOAD16(pB + c * 1024, bR + bgOff + c * 1024);
    #pragma unroll
    for (int c = 0; c < 4; ++c)
        GLOAD16(pB + 32768 + c * 1024, bN1 + bgOff + c * 1024);
    *(short8*)(aR + aWoff) = cvt8(t0, t1);
    asm volatile("s_waitcnt vmcnt(4)" ::: "memory");   // B0 done; B1 in flight
    asm volatile("s_waitcnt lgkmcnt(0)" ::: "memory");
    __builtin_amdgcn_s_barrier();

    // ---- main loop: kt = 0 .. NK-3 ----
    #pragma unroll 2
    for (int kt = 0; kt < NK - 2; ++kt) {
        // 1. issue kt+2 prefetch (B -> LDS ring, A -> regs)
        const char* ps = pB + (size_t)(kt + 2) * 32768;
        #pragma unroll
        for (int c = 0; c < 4; ++c)
            GLOAD16(ps + c * 1024, bN2 + bgOff + c * 1024);
        {
            const float* pa = pA + (kt + 2) * BK;
            rg[kt & 1][0] = *(const float4*)pa;
            rg[kt & 1][1] = *(const float4*)(pa + 4);
        }
        // 2. compute kt (published by previous barrier); lane*16 reads
        {
            short8 a[4], b[8];
            #pragma unroll
            for (int i = 0; i < 4; ++i)
                a[i] = *(const short8*)(aR + (wm * 4 + i) * 1024 + lane * 16);
            #pragma unroll
            for (int j = 0; j < 8; ++j)
                b[j] = *(const short8*)(bR + (wn * 8 + j) * 1024 + lane * 16);
            __builtin_amdgcn_s_setprio(1);
            #pragma unroll
            for (int i = 0; i < 4; ++i)
                #pragma unroll
                for (int j = 0; j < 8; ++j)
                    acc[i][j] = MFMA16(a[i], b[j], acc[i][j]);
            __builtin_amdgcn_s_setprio(0);
        }
        // 3. cvt+write A(kt+1) (compiler auto-waits counted vmcnt for rg)
        *(short8*)(aW + aWoff) = cvt8(rg[(kt + 1) & 1][0], rg[(kt + 1) & 1][1]);
        // 4. publish kt+1; kt+2's 6 loads stay in flight
        asm volatile("s_waitcnt vmcnt(6)" ::: "memory");
        asm volatile("s_waitcnt lgkmcnt(0)" ::: "memory");
        __builtin_amdgcn_s_barrier();
        { char* t = bR; bR = bN1; bN1 = bN2; bN2 = t; }
        { char* t = aR; aR = aW; aW = t; }
    }

    // ---- peeled kt = NK-2 ----
    {
        short8 a[4], b[8];
        #pragma unroll
        for (int i = 0; i < 4; ++i)
            a[i] = *(const short8*)(aR + (wm * 4 + i) * 1024 + lane * 16);
        #pragma unroll
        for (int j = 0; j < 8; ++j)
            b[j] = *(const short8*)(bR + (wn * 8 + j) * 1024 + lane * 16);
        __builtin_amdgcn_s_setprio(1);
        #pragma unroll
        for (int i = 0; i < 4; ++i)
            #pragma unroll
            for (int j = 0; j < 8; ++j)
                acc[i][j] = MFMA16(a[i], b[j], acc[i][j]);
        __builtin_amdgcn_s_setprio(0);
        *(short8*)(aW + aWoff) = cvt8(rg[(NK - 1) & 1][0], rg[(NK - 1) & 1][1]);
        asm volatile("s_waitcnt vmcnt(0)" ::: "memory");
        asm volatile("s_waitcnt lgkmcnt(0)" ::: "memory");
        __builtin_amdgcn_s_barrier();
        { char* t = bR; bR = bN1; bN1 = bN2; bN2 = t; }
        { char* t = aR; aR = aW; aW = t; }
    }
    // ---- peeled kt = NK-1 ----
    {
        short8 a[4], b[8];
        #pragma unroll
        for (int i = 0; i < 4; ++i)
            a[i] = *(const short8*)(aR + (wm * 4 + i) * 1024 + lane * 16);
        #pragma unroll
        for (int j = 0; j < 8; ++j)
            b[j] = *(const short8*)(bR + (wn * 8 + j) * 1024 + lane * 16);
        #pragma unroll
        for (int i = 0; i < 4; ++i)
            #pragma unroll
            for (int j = 0; j < 8; ++j)
                acc[i][j] = MFMA16(a[i], b[j], acc[i][j]);
    }

    // ---- epilogue: relu(acc + bias) . Wfull, reduce over a ----
    const int bf  = m0 / PIX;
    const int thr = (bf + 1) * PIX;
    const int bfc = (bf + 1 < BATCH) ? bf + 1 : BATCH - 1;
    float wf[8], bs0[8], bs1[8];
    #pragma unroll
    for (int j = 0; j < 8; ++j) {
        int aj = wn * 128 + j * 16 + cif;
        wf[j]  = Wfull[aj];
        bs0[j] = bias[(size_t)bf  * ADIM + aj];
        bs1[j] = bias[(size_t)bfc * ADIM + aj];
    }
    #pragma unroll
    for (int i = 0; i < 4; ++i) {
        #pragma unroll
        for (int r = 0; r < 4; ++r) {
            int ml = wm * 64 + i * 16 + rgrp * 4 + r;
            int m  = m0 + ml;
            bool sec = (m >= thr);
            float s = 0.f;
            #pragma unroll
            for (int j = 0; j < 8; ++j) {
                float v = acc[i][j][r] + (sec ? bs1[j] : bs0[j]);
                s += fmaxf(v, 0.f) * wf[j];
            }
            s += __shfl_xor(s, 1);
            s += __shfl_xor(s, 2);
            s += __shfl_xor(s, 4);
            s += __shfl_xor(s, 8);
            if (cif == 0) red[wn][ml] = s;
        }
    }
    __syncthreads();
    if (tid < 128)
        att[m0 + tid] = red[0][tid] + red[1][tid] + red[2][tid] + red[3][tid];
}

// ---------------------------------------------------------------------------
// Kernel 3: softmax over p (b_full cancels in softmax)
// ---------------------------------------------------------------------------
__global__ __launch_bounds__(256) void softmax_kernel(const float* __restrict__ att,
                                                      float* __restrict__ alpha) {
    const int b = blockIdx.x;
    const int tid = threadIdx.x;
    const int lane = tid & 63, wid = tid >> 6;
    __shared__ float wred[4];

    float x = (tid < PIX) ? att[(size_t)b * PIX + tid] : -1e30f;
    float m = x;
    #pragma unroll
    for (int off = 32; off >= 1; off >>= 1) m = fmaxf(m, __shfl_xor(m, off));
    if (lane == 0) wred[wid] = m;
    __syncthreads();
    float gm = fmaxf(fmaxf(wred[0], wred[1]), fmaxf(wred[2], wred[3]));
    __syncthreads();

    float e = (tid < PIX) ? __expf(x - gm) : 0.f;
    float s = e;
    #pragma unroll
    for (int off = 32; off >= 1; off >>= 1) s += __shfl_xor(s, off);
    if (lane == 0) wred[wid] = s;
    __syncthreads();
    float gs = wred[0] + wred[1] + wred[2] + wred[3];

    if (tid < PIX) alpha[(size_t)b * PIX + tid] = e / gs;
}

// ---------------------------------------------------------------------------
// Kernel 4: out[b][e] = sum_p enc[b][p][e] * alpha[b][p]
// ---------------------------------------------------------------------------
__global__ __launch_bounds__(128) void weighted_kernel(const float* __restrict__ enc,
                                                       const float* __restrict__ alpha,
                                                       float* __restrict__ out) {
    const int b = blockIdx.x >> 2;
    const int q = blockIdx.x & 3;
    const int tid = threadIdx.x;
    __shared__ float al[PIX];
    for (int i = tid; i < PIX; i += 128) al[i] = alpha[(size_t)b * PIX + i];
    __syncthreads();

    const int e = q * 512 + tid * 4;
    const float4* src = (const float4*)(enc + (size_t)b * PIX * EDIM + e);
    float ax = 0.f, ay = 0.f, az = 0.f, aw = 0.f;
    #pragma unroll 4
    for (int p = 0; p < PIX; p++) {
        float av = al[p];
        float4 v = src[(size_t)p * (EDIM / 4)];
        ax += av * v.x; ay += av * v.y; az += av * v.z; aw += av * v.w;
    }
    float4 o; o.x = ax; o.y = ay; o.z = az; o.w = aw;
    *(float4*)&out[(size_t)b * EDIM + e] = o;
}

// ---------------------------------------------------------------------------
extern "C" void kernel_launch(void* const* d_in, const int* in_sizes, int n_in,
                              void* d_out, int out_size, void* d_ws, size_t ws_size,
                              hipStream_t stream) {
    const float* enc   = (const float*)d_in[0];   // [128,196,2048]
    const float* dec   = (const float*)d_in[1];   // [128,512]
    const float* Wenc  = (const float*)d_in[2];   // [2048,512]
    const float* benc  = (const float*)d_in[3];   // [512]
    const float* Wdec  = (const float*)d_in[4];   // [512,512]
    const float* bdec  = (const float*)d_in[5];   // [512]
    const float* Wfull = (const float*)d_in[6];   // [512]
    // d_in[7] = b_full: constant shift, cancels in softmax

    float* out_awe   = (float*)d_out;                       // [128,2048]
    float* out_alpha = (float*)d_out + BATCH * EDIM;        // [128,196]

    char* ws = (char*)d_ws;
    unsigned short* WTp = (unsigned short*)ws;                      // 2 MB packed images
    float* bias = (float*)(ws + (size_t)ADIM * EDIM * 2);           // 256 KB [128][512]
    float* att  = (float*)(ws + (size_t)ADIM * EDIM * 2 + (size_t)BATCH * ADIM * 4);

    pack_wenc<<<NK, 256, 0, stream>>>(Wenc, WTp);
    bias_kernel<<<BATCH / 4, 256, 0, stream>>>(dec, Wdec, benc, bdec, bias);
    gemm_att<<<MTOT / 128, 512, 0, stream>>>(enc, WTp, bias, Wfull, att);
    softmax_kernel<<<BATCH, 256, 0, stream>>>(att, out_alpha);
    weighted_kernel<<<BATCH * 4, 128, 0, stream>>>(enc, out_alpha, out_awe);
}